// Round 19
// baseline (295.680 us; speedup 1.0000x reference)
//
#include <hip/hip_runtime.h>
#include <hip/hip_bf16.h>
#include <hip/hip_fp16.h>

typedef _Float16 f16;
typedef _Float16 f16x8 __attribute__((ext_vector_type(8)));
typedef float f32x4 __attribute__((ext_vector_type(4)));

#define SP 16384             // 128*128 spatial per batch
#define NTILES 4096
#define XF_BYTES ((size_t)NTILES * 40960)
#define PPB 8                // tile-pairs per persistent block (256*8*2 = 4096)

#define BAR_VM(N)                                                    \
  do {                                                               \
    asm volatile("s_waitcnt vmcnt(" #N ")" ::: "memory");            \
    __builtin_amdgcn_s_barrier();                                    \
    __builtin_amdgcn_sched_barrier(0);                               \
  } while (0)
#define BAR_LGKM()                                                   \
  do {                                                               \
    asm volatile("s_waitcnt lgkmcnt(0)" ::: "memory");               \
    __builtin_amdgcn_s_barrier();                                    \
    __builtin_amdgcn_sched_barrier(0);                               \
  } while (0)
// Bare barrier: per-wave LDS/global reads are complete by data dependency
// (consumed by MFMAs/VALU; vmcnt retires in order), so only cross-wave
// ordering is needed.
#define BAR_ONLY()                                                   \
  do {                                                               \
    __builtin_amdgcn_s_barrier();                                    \
    __builtin_amdgcn_sched_barrier(0);                               \
  } while (0)

// xf tile layout (40 KB per 16-spatial tile, LANE-LINEAR fragments):
//   byte = t*8192 + k0*1024 + g4*256 + c*16 + e*2 = x[t, d=k0*32+g4*8+e, s=16*tile+c]
// weight fragment layout (lane-linear, 1 KB per (mat,head,k0)):
//   wf f16 idx = ((mat*16+h)*8 + k0)*512 + lane*8 + e

__global__ __launch_bounds__(512) void prep_frag(const float* __restrict__ Wq,
                                                 const float* __restrict__ Wkv,
                                                 const float* __restrict__ Wp,
                                                 f16* __restrict__ wf) {
  const int gid = blockIdx.x * 512 + threadIdx.x;  // 0..32767
  const int mat = gid >> 13;
  const int rem = gid & 8191;
  const int h = rem >> 9;
  const int k0 = (rem >> 6) & 7;
  const int lane = rem & 63;
  const int c = lane & 15, g4 = lane >> 4;
  const int fr = h * 16 + c;
  const int kb = k0 * 32 + g4 * 8;
  f16x8 pk;
#pragma unroll
  for (int e = 0; e < 8; ++e) {
    float v;
    if (mat == 0)      v = Wq[(kb + e) * 256 + fr];
    else if (mat == 1) v = Wkv[(kb + e) * 512 + fr];
    else if (mat == 2) v = Wkv[(kb + e) * 512 + 256 + fr];
    else               v = Wp[(kb + e) * 256 + fr];
    pk[e] = (f16)v;
  }
  *(f16x8*)(wf + (size_t)gid * 8) = pk;
}

// Kernel A: transpose/cast x -> xf (fragment layout), full input.
__global__ __launch_bounds__(256) void xpose(const float* __restrict__ x,
                                             f16* __restrict__ xf) {
  __shared__ float ls[32 * 258];
  const int blk = blockIdx.x;
  const int sg = blk & 63;
  const int k0 = (blk >> 6) & 7;
  const int t  = (blk >> 9) % 5;
  const int bl = blk / 2560;
  const int tid = threadIdx.x;

  const float* xA = x + ((size_t)((bl * 5 + t) * 256 + k0 * 32)) * SP + sg * 256;
#pragma unroll
  for (int j = 0; j < 8; ++j) {
    const int qq = j * 256 + tid;
    const int dl = qq >> 6, s4 = qq & 63;
    const f32x4 v = *(const f32x4*)(xA + (size_t)dl * SP + s4 * 4);
    *(f32x4*)&ls[dl * 258 + s4 * 4] = v;
  }
  __syncthreads();

  const int tile_base = bl * 1024 + sg * 16;
#pragma unroll
  for (int pp = 0; pp < 4; ++pp) {
    const int piece = pp * 256 + tid;
    const int tt = piece >> 6;
    const int c  = (piece >> 2) & 15;
    const int g4 = piece & 3;
    f16x8 pk;
#pragma unroll
    for (int e = 0; e < 8; ++e)
      pk[e] = (f16)ls[(g4 * 8 + e) * 258 + tt * 16 + c];
    f16* dst = xf + (size_t)(tile_base + tt) * 20480 + t * 4096 + k0 * 512
                  + g4 * 128 + c * 8;
    *(f16x8*)dst = pk;
  }
}

// Kernel B: persistent, 1 block/CU, U=2, single-pass qkv, double-buffered
// pair staging. Bias/pos constants hoisted to registers before the pair loop
// (compiler wasn't hoisting: VGPR=80 at R16). qkv k-loop at unroll 4 —
// R17 proved the 2-waves/SIMD budget is >=300 regs (124 arch + 176 acc,
// spill-free), so deep pipelining is affordable.
__global__ __launch_bounds__(512, 2) void fused(
    const f16* __restrict__ xf,
    const float* __restrict__ bq,
    const float* __restrict__ bkv,
    const float* __restrict__ bp,
    const float* __restrict__ pos_bias,
    const f16* __restrict__ wf,
    float* __restrict__ out) {
  __shared__ __align__(16) char lds[163840];  // X0=[0,80K), X1=[80K,160K)

  const int tid = threadIdx.x;
  const int lane = tid & 63;
  const int w = tid >> 6;    // wave 0..7 -> heads 2w, 2w+1
  const int c = lane & 15;
  const int g4 = lane >> 4;
  const int hA = 2 * w;

  const f16* wfq = wf;
  const f16* wfk = wf + 65536;
  const f16* wfv = wf + 131072;
  const f16* wfp = wf + 196608;

  const int pair0 = blockIdx.x * PPB;

  // ---- hoisted per-head constants (pair-invariant; ~36 regs) ----
  float pb[2][5], bqr[2][4], bkr[2][4], bvr[2][4], bpv[2];
#pragma unroll
  for (int j = 0; j < 2; ++j) {
    const int hj = hA + j;
    bpv[j] = bp[hj * 16 + c];
#pragma unroll
    for (int t = 0; t < 5; ++t) pb[j][t] = pos_bias[hj * 5 + t];
#pragma unroll
    for (int rr = 0; rr < 4; ++rr) {
      bqr[j][rr] = bq[hj * 16 + 4 * g4 + rr];
      bkr[j][rr] = bkv[hj * 16 + 4 * g4 + rr];
      bvr[j][rr] = bkv[256 + hj * 16 + 4 * g4 + rr];
    }
  }

  // stage pair p (80 KB contiguous in xf) into buffer buf: 10 glls/wave
  auto stage_pair = [&](int p, int buf) {
    const char* src = (const char*)xf + (size_t)p * 81920 + w * 5120 + lane * 16;
    char* dst = lds + buf * 81920 + w * 5120 + lane * 16;
#pragma unroll
    for (int u = 0; u < 2; ++u)
#pragma unroll
      for (int n = 0; n < 5; ++n)
        __builtin_amdgcn_global_load_lds(
            (const void __attribute__((address_space(1)))*)(src + u * 40960 + n * 1024),
            (void __attribute__((address_space(3)))*)(dst + u * 40960 + n * 1024),
            16, 0, 0);
  };

  stage_pair(pair0, 0);
  BAR_VM(0);  // prologue: X0 fully visible

  for (int i = 0; i < PPB; ++i) {
    const int buf = i & 1;
    char* Xb = lds + buf * 81920;

    if (i > 0) BAR_ONLY();  // stage(i) glls already retired in-order during
                            // pair i-1's k-loop; barrier orders waves only

    // issue next pair's staging (retires during this pair's k-loop)
    if (i + 1 < PPB) stage_pair(pair0 + i + 1, buf ^ 1);

    // ---- single-pass q/k/v GEMM, both tiles (C[m=dk][n=s]) ----
    f32x4 qacc[2][2] = {};      // [tile][head]
    f32x4 kacc[2][2][5] = {};
    f32x4 vacc[2][2][5] = {};
#pragma unroll 4
    for (int k0 = 0; k0 < 8; ++k0) {
      const int wb = k0 * 512 + lane * 8;
      const f16x8 fq0 = *(const f16x8*)(wfq + hA * 4096 + wb);
      const f16x8 fq1 = *(const f16x8*)(wfq + (hA + 1) * 4096 + wb);
      const f16x8 fk0 = *(const f16x8*)(wfk + hA * 4096 + wb);
      const f16x8 fk1 = *(const f16x8*)(wfk + (hA + 1) * 4096 + wb);
      const f16x8 fv0 = *(const f16x8*)(wfv + hA * 4096 + wb);
      const f16x8 fv1 = *(const f16x8*)(wfv + (hA + 1) * 4096 + wb);
      const int base = (k0 << 10) + (g4 << 8) + (c << 4);
#pragma unroll
      for (int u = 0; u < 2; ++u) {
        const char* fbp = Xb + u * 40960;
        f16x8 xfr[5];
#pragma unroll
        for (int t = 0; t < 5; ++t) xfr[t] = *(const f16x8*)(fbp + (t << 13) + base);
        qacc[u][0] = __builtin_amdgcn_mfma_f32_16x16x32_f16(fq0, xfr[0], qacc[u][0], 0, 0, 0);
        qacc[u][1] = __builtin_amdgcn_mfma_f32_16x16x32_f16(fq1, xfr[0], qacc[u][1], 0, 0, 0);
#pragma unroll
        for (int t = 0; t < 5; ++t) {
          kacc[u][0][t] = __builtin_amdgcn_mfma_f32_16x16x32_f16(fk0, xfr[t], kacc[u][0][t], 0, 0, 0);
          kacc[u][1][t] = __builtin_amdgcn_mfma_f32_16x16x32_f16(fk1, xfr[t], kacc[u][1][t], 0, 0, 0);
          vacc[u][0][t] = __builtin_amdgcn_mfma_f32_16x16x32_f16(fv0, xfr[t], vacc[u][0][t], 0, 0, 0);
          vacc[u][1][t] = __builtin_amdgcn_mfma_f32_16x16x32_f16(fv1, xfr[t], vacc[u][1][t], 0, 0, 0);
        }
      }
    }

    // ---- attention, fully in-register (constants pre-hoisted) ----
    f32x4 o[2][2];
#pragma unroll
    for (int j = 0; j < 2; ++j) {
#pragma unroll
      for (int u = 0; u < 2; ++u) {
        float qv[4];
#pragma unroll
        for (int rr = 0; rr < 4; ++rr) qv[rr] = qacc[u][j][rr] + bqr[j][rr];
        float sc[5];
#pragma unroll
        for (int t = 0; t < 5; ++t) {
          float p = 0.f;
#pragma unroll
          for (int rr = 0; rr < 4; ++rr) p += qv[rr] * (kacc[u][j][t][rr] + bkr[j][rr]);
          p += __shfl_xor(p, 16);
          p += __shfl_xor(p, 32);
          sc[t] = p * 4.0f + pb[j][t];  // /temperature (=0.25) + pos_bias
        }
        float m = sc[0];
#pragma unroll
        for (int t = 1; t < 5; ++t) m = fmaxf(m, sc[t]);
        float l = 0.f;
#pragma unroll
        for (int t = 0; t < 5; ++t) { sc[t] = __expf(sc[t] - m); l += sc[t]; }
        const float inv = 1.0f / l;
        f32x4 oo = {};
#pragma unroll
        for (int t = 0; t < 5; ++t)
#pragma unroll
          for (int rr = 0; rr < 4; ++rr) oo[rr] += sc[t] * vacc[u][j][t][rr];
#pragma unroll
        for (int rr = 0; rr < 4; ++rr) oo[rr] = oo[rr] * inv + bvr[j][rr];
        o[u][j] = oo;
      }
    }

    BAR_ONLY();  // bar_A: cross-wave ordering only

    // ---- write as_ overlay (first 16 KB of Xb; lane-linear b64) ----
#pragma unroll
    for (int u = 0; u < 2; ++u)
#pragma unroll
      for (int j = 0; j < 2; ++j) {
        union { f16 hh[4]; unsigned long long uu; } pk;
#pragma unroll
        for (int rr = 0; rr < 4; ++rr) pk.hh[rr] = (f16)o[u][j][rr];
        const int byte = (w << 10) + ((2 * j + (g4 >> 1)) << 8) + (c << 4)
                         + ((g4 & 1) << 3);
        *(unsigned long long*)(Xb + u * 8192 + byte) = pk.uu;
      }
    BAR_LGKM();  // bar_B: as_ ds_writes complete + visible to all waves

    // ---- projection ----
    f32x4 facc[2][2] = {};
#pragma unroll 2
    for (int k0 = 0; k0 < 8; ++k0) {
      const int wb = k0 * 512 + lane * 8;
      const f16x8 f0 = *(const f16x8*)(wfp + hA * 4096 + wb);
      const f16x8 f1 = *(const f16x8*)(wfp + (hA + 1) * 4096 + wb);
      const int abyte = (k0 << 10) + (g4 << 8) + (c << 4);
#pragma unroll
      for (int u = 0; u < 2; ++u) {
        const f16x8 af = *(const f16x8*)(Xb + u * 8192 + abyte);
        facc[u][0] = __builtin_amdgcn_mfma_f32_16x16x32_f16(af, f0, facc[u][0], 0, 0, 0);
        facc[u][1] = __builtin_amdgcn_mfma_f32_16x16x32_f16(af, f1, facc[u][1], 0, 0, 0);
      }
    }

    // ---- store (4 f32x4/wave; retire during next pair's k-loop) ----
#pragma unroll
    for (int u = 0; u < 2; ++u) {
      const int g = (pair0 + i) * 2 + u;
      const int b = g >> 10, s0 = (g & 1023) << 4;
#pragma unroll
      for (int j = 0; j < 2; ++j) {
        const int dg = (hA + j) * 16 + c;
        f32x4 vs = facc[u][j];
#pragma unroll
        for (int rr = 0; rr < 4; ++rr) vs[rr] += bpv[j];
        float* dst = out + ((size_t)b * 256 + dg) * SP + s0 + (g4 << 2);
        *(f32x4*)dst = vs;
      }
    }
    // no bar_C: next write to Xb is stage(i+2), behind next pair-top barrier
  }
}

extern "C" void kernel_launch(void* const* d_in, const int* in_sizes, int n_in,
                              void* d_out, int out_size, void* d_ws, size_t ws_size,
                              hipStream_t stream) {
  const float* x   = (const float*)d_in[0];
  const float* Wq  = (const float*)d_in[1];
  const float* bq  = (const float*)d_in[2];
  const float* Wkv = (const float*)d_in[3];
  const float* bkv = (const float*)d_in[4];
  const float* Wp  = (const float*)d_in[5];
  const float* bp  = (const float*)d_in[6];
  const float* pos = (const float*)d_in[7];

  f16* xf = (f16*)d_ws;                        // 168 MB
  f16* wf = (f16*)((char*)d_ws + XF_BYTES);    // 512 KB fragment weights

  prep_frag<<<64, 512, 0, stream>>>(Wq, Wkv, Wp, wf);
  xpose<<<10240, 256, 0, stream>>>(x, xf);
  fused<<<256, 512, 0, stream>>>(xf, bq, bkv, bp, pos, wf, (float*)d_out);
}

// Round 20
// 249.365 us; speedup vs baseline: 1.1857x; 1.1857x over previous
//
#include <hip/hip_runtime.h>
#include <hip/hip_bf16.h>
#include <hip/hip_fp16.h>

typedef _Float16 f16;
typedef _Float16 f16x8 __attribute__((ext_vector_type(8)));
typedef float f32x4 __attribute__((ext_vector_type(4)));

#define SP 16384             // 128*128 spatial per batch
#define NTILES 4096
#define XF_BYTES ((size_t)NTILES * 40960)
#define PPB 8                // tile-pairs per persistent block (256*8*2 = 4096)

#define BAR_VM(N)                                                    \
  do {                                                               \
    asm volatile("s_waitcnt vmcnt(" #N ")" ::: "memory");            \
    __builtin_amdgcn_s_barrier();                                    \
    __builtin_amdgcn_sched_barrier(0);                               \
  } while (0)
#define BAR_LGKM()                                                   \
  do {                                                               \
    asm volatile("s_waitcnt lgkmcnt(0)" ::: "memory");               \
    __builtin_amdgcn_s_barrier();                                    \
    __builtin_amdgcn_sched_barrier(0);                               \
  } while (0)
#define BAR_ONLY()                                                   \
  do {                                                               \
    __builtin_amdgcn_s_barrier();                                    \
    __builtin_amdgcn_sched_barrier(0);                               \
  } while (0)

// xf tile layout (40 KB per 16-spatial tile, LANE-LINEAR fragments):
//   byte = t*8192 + k0*1024 + g4*256 + c*16 + e*2 = x[t, d=k0*32+g4*8+e, s=16*tile+c]
// weight fragment layout (lane-linear, 1 KB per (mat,head,k0)):
//   wf f16 idx = ((mat*16+h)*8 + k0)*512 + lane*8 + e
// as_ layout (8 KB per tile): byte(feat,s) =
//   (feat>>5)*1024 + ((feat>>3)&3)*256 + s*16 + (feat&7)*2

__global__ __launch_bounds__(512) void prep_frag(const float* __restrict__ Wq,
                                                 const float* __restrict__ Wkv,
                                                 const float* __restrict__ Wp,
                                                 f16* __restrict__ wf) {
  const int gid = blockIdx.x * 512 + threadIdx.x;  // 0..32767
  const int mat = gid >> 13;
  const int rem = gid & 8191;
  const int h = rem >> 9;
  const int k0 = (rem >> 6) & 7;
  const int lane = rem & 63;
  const int c = lane & 15, g4 = lane >> 4;
  const int fr = h * 16 + c;
  const int kb = k0 * 32 + g4 * 8;
  f16x8 pk;
#pragma unroll
  for (int e = 0; e < 8; ++e) {
    float v;
    if (mat == 0)      v = Wq[(kb + e) * 256 + fr];
    else if (mat == 1) v = Wkv[(kb + e) * 512 + fr];
    else if (mat == 2) v = Wkv[(kb + e) * 512 + 256 + fr];
    else               v = Wp[(kb + e) * 256 + fr];
    pk[e] = (f16)v;
  }
  *(f16x8*)(wf + (size_t)gid * 8) = pk;
}

// Kernel A: transpose/cast x -> xf (fragment layout), full input.
__global__ __launch_bounds__(256) void xpose(const float* __restrict__ x,
                                             f16* __restrict__ xf) {
  __shared__ float ls[32 * 258];
  const int blk = blockIdx.x;
  const int sg = blk & 63;
  const int k0 = (blk >> 6) & 7;
  const int t  = (blk >> 9) % 5;
  const int bl = blk / 2560;
  const int tid = threadIdx.x;

  const float* xA = x + ((size_t)((bl * 5 + t) * 256 + k0 * 32)) * SP + sg * 256;
#pragma unroll
  for (int j = 0; j < 8; ++j) {
    const int qq = j * 256 + tid;
    const int dl = qq >> 6, s4 = qq & 63;
    const f32x4 v = *(const f32x4*)(xA + (size_t)dl * SP + s4 * 4);
    *(f32x4*)&ls[dl * 258 + s4 * 4] = v;
  }
  __syncthreads();

  const int tile_base = bl * 1024 + sg * 16;
#pragma unroll
  for (int pp = 0; pp < 4; ++pp) {
    const int piece = pp * 256 + tid;
    const int tt = piece >> 6;
    const int c  = (piece >> 2) & 15;
    const int g4 = piece & 3;
    f16x8 pk;
#pragma unroll
    for (int e = 0; e < 8; ++e)
      pk[e] = (f16)ls[(g4 * 8 + e) * 258 + tt * 16 + c];
    f16* dst = xf + (size_t)(tile_base + tt) * 20480 + t * 4096 + k0 * 512
                  + g4 * 128 + c * 8;
    *(f16x8*)dst = pk;
  }
}

// Kernel B: persistent, 1024 threads = 16 waves, wave = 1 head, U=2 pair,
// TWO-PASS (pass1 q+k acc=48 -> softmax keeps e -> pass2 v in t-groups).
// Peak live ~110 regs -> fits the 128 cap at (1024,4): 4 waves/SIMD =
// 2x the TLP of the acc-176 single-pass jail. Counted-vmcnt dbuf staging.
__global__ __launch_bounds__(1024, 4) void fused(
    const f16* __restrict__ xf,
    const float* __restrict__ bq,
    const float* __restrict__ bkv,
    const float* __restrict__ bp,
    const float* __restrict__ pos_bias,
    const f16* __restrict__ wf,
    float* __restrict__ out) {
  __shared__ __align__(16) char lds[163840];  // X0=[0,80K), X1=[80K,160K)

  const int tid = threadIdx.x;
  const int lane = tid & 63;
  const int w = tid >> 6;    // wave 0..15 = head
  const int c = lane & 15;
  const int g4 = lane >> 4;

  const f16* wq_ = wf + (size_t)(0 * 16 + w) * 4096 + lane * 8;
  const f16* wk_ = wf + (size_t)(1 * 16 + w) * 4096 + lane * 8;
  const f16* wv_ = wf + (size_t)(2 * 16 + w) * 4096 + lane * 8;
  const f16* wp_ = wf + (size_t)(3 * 16 + w) * 4096 + lane * 8;

  const int pair0 = blockIdx.x * PPB;

  // ---- hoisted per-head constants (18 regs) ----
  float pb[5], bqr[4], bkr[4], bvr[4], bpv;
  bpv = bp[w * 16 + c];
#pragma unroll
  for (int t = 0; t < 5; ++t) pb[t] = pos_bias[w * 5 + t];
#pragma unroll
  for (int rr = 0; rr < 4; ++rr) {
    bqr[rr] = bq[w * 16 + 4 * g4 + rr];
    bkr[rr] = bkv[w * 16 + 4 * g4 + rr];
    bvr[rr] = bkv[256 + w * 16 + 4 * g4 + rr];
  }

  // stage pair p (80 KB) into buffer buf: 5 glls per wave (16 waves)
  auto stage_pair = [&](int p, int buf) {
    const char* src = (const char*)xf + (size_t)p * 81920 + w * 5120 + lane * 16;
    char* dst = lds + buf * 81920 + w * 5120 + lane * 16;
#pragma unroll
    for (int n = 0; n < 5; ++n)
      __builtin_amdgcn_global_load_lds(
          (const void __attribute__((address_space(1)))*)(src + n * 1024),
          (void __attribute__((address_space(3)))*)(dst + n * 1024), 16, 0, 0);
  };

  stage_pair(pair0, 0);
  BAR_VM(0);  // prologue: X0 fully visible

  for (int i = 0; i < PPB; ++i) {
    const int buf = i & 1;
    char* Xb = lds + buf * 81920;

    if (i > 0) BAR_VM(2);  // stage(i) glls retired (in-order, behind pair
                           // i-1's loads); leave the 2 newest stores pending

    if (i + 1 < PPB) stage_pair(pair0 + i + 1, buf ^ 1);

    // ---- pass 1: q + k GEMM, both tiles (C[m=dk][n=s]); acc = 48 ----
    f32x4 qa[2] = {};
    f32x4 ka[2][5] = {};
#pragma unroll 1
    for (int k0 = 0; k0 < 8; ++k0) {
      const f16x8 fq = *(const f16x8*)(wq_ + k0 * 512);
      const f16x8 fk = *(const f16x8*)(wk_ + k0 * 512);
      const int base = (k0 << 10) + (g4 << 8) + (c << 4);
#pragma unroll
      for (int u = 0; u < 2; ++u) {
        const char* fbp = Xb + u * 40960;
        f16x8 xfr[5];
#pragma unroll
        for (int t = 0; t < 5; ++t) xfr[t] = *(const f16x8*)(fbp + (t << 13) + base);
        qa[u] = __builtin_amdgcn_mfma_f32_16x16x32_f16(fq, xfr[0], qa[u], 0, 0, 0);
#pragma unroll
        for (int t = 0; t < 5; ++t)
          ka[u][t] = __builtin_amdgcn_mfma_f32_16x16x32_f16(fk, xfr[t], ka[u][t], 0, 0, 0);
      }
    }

    // ---- softmax: keep e (unnormalized) + inv ----
    float e[2][5], inv_[2];
#pragma unroll
    for (int u = 0; u < 2; ++u) {
      float qv[4];
#pragma unroll
      for (int rr = 0; rr < 4; ++rr) qv[rr] = qa[u][rr] + bqr[rr];
      float sc[5];
#pragma unroll
      for (int t = 0; t < 5; ++t) {
        float p = 0.f;
#pragma unroll
        for (int rr = 0; rr < 4; ++rr) p += qv[rr] * (ka[u][t][rr] + bkr[rr]);
        p += __shfl_xor(p, 16);
        p += __shfl_xor(p, 32);
        sc[t] = p * 4.0f + pb[t];  // /temperature (=0.25) + pos_bias
      }
      float m = sc[0];
#pragma unroll
      for (int t = 1; t < 5; ++t) m = fmaxf(m, sc[t]);
      float l = 0.f;
#pragma unroll
      for (int t = 0; t < 5; ++t) { e[u][t] = __expf(sc[t] - m); l += e[u][t]; }
      inv_[u] = 1.0f / l;
    }

    // ---- pass 2: v GEMM in t-groups {0,1},{2,3},{4}; va <= 16 live ----
    f32x4 o[2] = {};
#pragma unroll
    for (int gi = 0; gi < 3; ++gi) {         // fully unrolled: static e idx
      const int tg = gi * 2;
      const int nt = (gi == 2) ? 1 : 2;
      f32x4 va[2][2] = {};                    // [ti][tile]
#pragma unroll 1
      for (int k0 = 0; k0 < 8; ++k0) {
        const f16x8 fv = *(const f16x8*)(wv_ + k0 * 512);
        const int base = (k0 << 10) + (g4 << 8) + (c << 4);
#pragma unroll
        for (int u = 0; u < 2; ++u) {
          const char* fbp = Xb + u * 40960;
#pragma unroll
          for (int ti = 0; ti < 2; ++ti)
            if (ti < nt) {
              const f16x8 xfr = *(const f16x8*)(fbp + ((tg + ti) << 13) + base);
              va[ti][u] = __builtin_amdgcn_mfma_f32_16x16x32_f16(fv, xfr, va[ti][u], 0, 0, 0);
            }
        }
      }
#pragma unroll
      for (int ti = 0; ti < 2; ++ti)
        if (ti < nt)
#pragma unroll
          for (int u = 0; u < 2; ++u)
#pragma unroll
            for (int rr = 0; rr < 4; ++rr)
              o[u][rr] += e[u][tg + ti] * va[ti][u][rr];
    }

    BAR_ONLY();  // bar_A: all Xb reads done across waves

    // ---- write as_ overlay (first 16 KB of Xb; one b64 per tile) ----
#pragma unroll
    for (int u = 0; u < 2; ++u) {
      union { f16 hh[4]; unsigned long long uu; } pk;
#pragma unroll
      for (int rr = 0; rr < 4; ++rr)
        pk.hh[rr] = (f16)(o[u][rr] * inv_[u] + bvr[rr]);  // sum(p)=1
      const int byte = ((w >> 1) << 10) + (((2 * w + (g4 >> 1)) & 3) << 8)
                       + (c << 4) + ((g4 & 1) << 3);
      *(unsigned long long*)(Xb + u * 8192 + byte) = pk.uu;
    }
    BAR_LGKM();  // bar_B: as_ visible

    // ---- projection: wave w -> douts 16w..16w+15 ----
    f32x4 fa[2] = {};
#pragma unroll 2
    for (int k0 = 0; k0 < 8; ++k0) {
      const f16x8 fp = *(const f16x8*)(wp_ + k0 * 512);
      const int abyte = (k0 << 10) + (g4 << 8) + (c << 4);
#pragma unroll
      for (int u = 0; u < 2; ++u) {
        const f16x8 af = *(const f16x8*)(Xb + u * 8192 + abyte);
        fa[u] = __builtin_amdgcn_mfma_f32_16x16x32_f16(af, fp, fa[u], 0, 0, 0);
      }
    }

    // ---- store (2 f32x4/wave; retire during next pair's pass 1) ----
#pragma unroll
    for (int u = 0; u < 2; ++u) {
      const int g = (pair0 + i) * 2 + u;
      const int b = g >> 10, s0 = (g & 1023) << 4;
      const int dg = w * 16 + c;
      f32x4 vs = fa[u];
#pragma unroll
      for (int rr = 0; rr < 4; ++rr) vs[rr] += bpv;
      *(f32x4*)(out + ((size_t)b * 256 + dg) * SP + s0 + (g4 << 2)) = vs;
    }
    // no bar_C: next write to Xb is stage(i+2), behind next pair-top barrier
  }
}

extern "C" void kernel_launch(void* const* d_in, const int* in_sizes, int n_in,
                              void* d_out, int out_size, void* d_ws, size_t ws_size,
                              hipStream_t stream) {
  const float* x   = (const float*)d_in[0];
  const float* Wq  = (const float*)d_in[1];
  const float* bq  = (const float*)d_in[2];
  const float* Wkv = (const float*)d_in[3];
  const float* bkv = (const float*)d_in[4];
  const float* Wp  = (const float*)d_in[5];
  const float* bp  = (const float*)d_in[6];
  const float* pos = (const float*)d_in[7];

  f16* xf = (f16*)d_ws;                        // 168 MB
  f16* wf = (f16*)((char*)d_ws + XF_BYTES);    // 512 KB fragment weights

  prep_frag<<<64, 512, 0, stream>>>(Wq, Wkv, Wp, wf);
  xpose<<<10240, 256, 0, stream>>>(x, xf);
  fused<<<256, 1024, 0, stream>>>(xf, bq, bkv, bp, pos, wf, (float*)d_out);
}

// Round 21
// 233.406 us; speedup vs baseline: 1.2668x; 1.0684x over previous
//
#include <hip/hip_runtime.h>
#include <hip/hip_bf16.h>
#include <hip/hip_fp16.h>

typedef _Float16 f16;
typedef _Float16 f16x8 __attribute__((ext_vector_type(8)));
typedef float f32x4 __attribute__((ext_vector_type(4)));

#define SP 16384             // 128*128 spatial per batch
#define NTILES 4096
#define XF_BYTES ((size_t)NTILES * 40960)
#define PPB 8                // tile-pairs per persistent block (256*8*2 = 4096)

// Counted-waitcnt barriers (T4): __syncthreads would drain vmcnt(0) and
// kill cross-pair staging overlap.
#define BAR_VM(N)                                                    \
  do {                                                               \
    asm volatile("s_waitcnt vmcnt(" #N ")" ::: "memory");            \
    __builtin_amdgcn_s_barrier();                                    \
    __builtin_amdgcn_sched_barrier(0);                               \
  } while (0)
#define BAR_LGKM()                                                   \
  do {                                                               \
    asm volatile("s_waitcnt lgkmcnt(0)" ::: "memory");               \
    __builtin_amdgcn_s_barrier();                                    \
    __builtin_amdgcn_sched_barrier(0);                               \
  } while (0)
// Bare barrier: per-wave LDS reads are already complete by data dependency
// (their values fed MFMAs); only cross-wave ordering is needed.
#define BAR_ONLY()                                                   \
  do {                                                               \
    __builtin_amdgcn_s_barrier();                                    \
    __builtin_amdgcn_sched_barrier(0);                               \
  } while (0)

// xf tile layout (40 KB per 16-spatial tile, LANE-LINEAR fragments):
//   byte = t*8192 + k0*1024 + g4*256 + c*16 + e*2 = x[t, d=k0*32+g4*8+e, s=16*tile+c]
// weight fragment layout (lane-linear, 1 KB per (mat,head,k0)):
//   wf f16 idx = ((mat*16+h)*8 + k0)*512 + lane*8 + e

__global__ __launch_bounds__(512) void prep_frag(const float* __restrict__ Wq,
                                                 const float* __restrict__ Wkv,
                                                 const float* __restrict__ Wp,
                                                 f16* __restrict__ wf) {
  const int gid = blockIdx.x * 512 + threadIdx.x;  // 0..32767
  const int mat = gid >> 13;
  const int rem = gid & 8191;
  const int h = rem >> 9;
  const int k0 = (rem >> 6) & 7;
  const int lane = rem & 63;
  const int c = lane & 15, g4 = lane >> 4;
  const int fr = h * 16 + c;
  const int kb = k0 * 32 + g4 * 8;
  f16x8 pk;
#pragma unroll
  for (int e = 0; e < 8; ++e) {
    float v;
    if (mat == 0)      v = Wq[(kb + e) * 256 + fr];
    else if (mat == 1) v = Wkv[(kb + e) * 512 + fr];
    else if (mat == 2) v = Wkv[(kb + e) * 512 + 256 + fr];
    else               v = Wp[(kb + e) * 256 + fr];
    pk[e] = (f16)v;
  }
  *(f16x8*)(wf + (size_t)gid * 8) = pk;
}

// Kernel A: transpose/cast x -> xf (fragment layout), full input.
__global__ __launch_bounds__(256) void xpose(const float* __restrict__ x,
                                             f16* __restrict__ xf) {
  __shared__ float ls[32 * 258];
  const int blk = blockIdx.x;
  const int sg = blk & 63;
  const int k0 = (blk >> 6) & 7;
  const int t  = (blk >> 9) % 5;
  const int bl = blk / 2560;
  const int tid = threadIdx.x;

  const float* xA = x + ((size_t)((bl * 5 + t) * 256 + k0 * 32)) * SP + sg * 256;
#pragma unroll
  for (int j = 0; j < 8; ++j) {
    const int qq = j * 256 + tid;
    const int dl = qq >> 6, s4 = qq & 63;
    const f32x4 v = *(const f32x4*)(xA + (size_t)dl * SP + s4 * 4);
    *(f32x4*)&ls[dl * 258 + s4 * 4] = v;
  }
  __syncthreads();

  const int tile_base = bl * 1024 + sg * 16;
#pragma unroll
  for (int pp = 0; pp < 4; ++pp) {
    const int piece = pp * 256 + tid;
    const int tt = piece >> 6;
    const int c  = (piece >> 2) & 15;
    const int g4 = piece & 3;
    f16x8 pk;
#pragma unroll
    for (int e = 0; e < 8; ++e)
      pk[e] = (f16)ls[(g4 * 8 + e) * 258 + tt * 16 + c];
    f16* dst = xf + (size_t)(tile_base + tt) * 20480 + t * 4096 + k0 * 512
                  + g4 * 128 + c * 8;
    *(f16x8*)dst = pk;
  }
}

// Kernel B: persistent, 1 block/CU, U=2, single-pass qkv, counted-vmcnt
// double-buffered pair staging. qkv k-loop at unroll 2 (proven optimum:
// unroll 4 + hoisting spilled in R19; acc-176 + ~100 arch is the balance
// point at 2 waves/SIMD). Proj k-loop at unroll 4 — qkv accs are dead
// there, register pressure is low, so deeper pipelining is free.
__global__ __launch_bounds__(512, 2) void fused(
    const f16* __restrict__ xf,
    const float* __restrict__ bq,
    const float* __restrict__ bkv,
    const float* __restrict__ bp,
    const float* __restrict__ pos_bias,
    const f16* __restrict__ wf,
    float* __restrict__ out) {
  __shared__ __align__(16) char lds[163840];  // X0=[0,80K), X1=[80K,160K)

  const int tid = threadIdx.x;
  const int lane = tid & 63;
  const int w = tid >> 6;    // wave 0..7 -> heads 2w, 2w+1
  const int c = lane & 15;
  const int g4 = lane >> 4;
  const int hA = 2 * w;

  const f16* wfq = wf;
  const f16* wfk = wf + 65536;
  const f16* wfv = wf + 131072;
  const f16* wfp = wf + 196608;

  const int pair0 = blockIdx.x * PPB;

  // stage pair p (80 KB contiguous in xf) into buffer buf: 10 glls/wave
  auto stage_pair = [&](int p, int buf) {
    const char* src = (const char*)xf + (size_t)p * 81920 + w * 5120 + lane * 16;
    char* dst = lds + buf * 81920 + w * 5120 + lane * 16;
#pragma unroll
    for (int u = 0; u < 2; ++u)
#pragma unroll
      for (int n = 0; n < 5; ++n)
        __builtin_amdgcn_global_load_lds(
            (const void __attribute__((address_space(1)))*)(src + u * 40960 + n * 1024),
            (void __attribute__((address_space(3)))*)(dst + u * 40960 + n * 1024),
            16, 0, 0);
  };

  stage_pair(pair0, 0);
  BAR_VM(0);  // prologue: X0 fully visible

  for (int i = 0; i < PPB; ++i) {
    const int buf = i & 1;
    char* Xb = lds + buf * 81920;

    if (i > 0) BAR_VM(4);  // drain stage(i); leave 4 newest (prev stores)

    // issue next pair's staging; drains only at NEXT pair-top vmcnt(4)
    if (i + 1 < PPB) stage_pair(pair0 + i + 1, buf ^ 1);

    // ---- single-pass q/k/v GEMM, both tiles (C[m=dk][n=s]) ----
    f32x4 qacc[2][2] = {};      // [tile][head]
    f32x4 kacc[2][2][5] = {};
    f32x4 vacc[2][2][5] = {};
#pragma unroll 2
    for (int k0 = 0; k0 < 8; ++k0) {
      const int wb = k0 * 512 + lane * 8;
      const f16x8 fq0 = *(const f16x8*)(wfq + hA * 4096 + wb);
      const f16x8 fq1 = *(const f16x8*)(wfq + (hA + 1) * 4096 + wb);
      const f16x8 fk0 = *(const f16x8*)(wfk + hA * 4096 + wb);
      const f16x8 fk1 = *(const f16x8*)(wfk + (hA + 1) * 4096 + wb);
      const f16x8 fv0 = *(const f16x8*)(wfv + hA * 4096 + wb);
      const f16x8 fv1 = *(const f16x8*)(wfv + (hA + 1) * 4096 + wb);
      const int base = (k0 << 10) + (g4 << 8) + (c << 4);
#pragma unroll
      for (int u = 0; u < 2; ++u) {
        const char* fbp = Xb + u * 40960;
        f16x8 xfr[5];
#pragma unroll
        for (int t = 0; t < 5; ++t) xfr[t] = *(const f16x8*)(fbp + (t << 13) + base);
        qacc[u][0] = __builtin_amdgcn_mfma_f32_16x16x32_f16(fq0, xfr[0], qacc[u][0], 0, 0, 0);
        qacc[u][1] = __builtin_amdgcn_mfma_f32_16x16x32_f16(fq1, xfr[0], qacc[u][1], 0, 0, 0);
#pragma unroll
        for (int t = 0; t < 5; ++t) {
          kacc[u][0][t] = __builtin_amdgcn_mfma_f32_16x16x32_f16(fk0, xfr[t], kacc[u][0][t], 0, 0, 0);
          kacc[u][1][t] = __builtin_amdgcn_mfma_f32_16x16x32_f16(fk1, xfr[t], kacc[u][1][t], 0, 0, 0);
          vacc[u][0][t] = __builtin_amdgcn_mfma_f32_16x16x32_f16(fv0, xfr[t], vacc[u][0][t], 0, 0, 0);
          vacc[u][1][t] = __builtin_amdgcn_mfma_f32_16x16x32_f16(fv1, xfr[t], vacc[u][1][t], 0, 0, 0);
        }
      }
    }

    // ---- attention, fully in-register ----
    f32x4 o[2][2];
#pragma unroll
    for (int j = 0; j < 2; ++j) {
      const int hj = hA + j;
      float bqr[4], bkr[4], bvr[4], pb[5];
#pragma unroll
      for (int t = 0; t < 5; ++t) pb[t] = pos_bias[hj * 5 + t];
#pragma unroll
      for (int rr = 0; rr < 4; ++rr) {
        bqr[rr] = bq[hj * 16 + 4 * g4 + rr];
        bkr[rr] = bkv[hj * 16 + 4 * g4 + rr];
        bvr[rr] = bkv[256 + hj * 16 + 4 * g4 + rr];
      }
#pragma unroll
      for (int u = 0; u < 2; ++u) {
        float qv[4];
#pragma unroll
        for (int rr = 0; rr < 4; ++rr) qv[rr] = qacc[u][j][rr] + bqr[rr];
        float sc[5];
#pragma unroll
        for (int t = 0; t < 5; ++t) {
          float p = 0.f;
#pragma unroll
          for (int rr = 0; rr < 4; ++rr) p += qv[rr] * (kacc[u][j][t][rr] + bkr[rr]);
          p += __shfl_xor(p, 16);
          p += __shfl_xor(p, 32);
          sc[t] = p * 4.0f + pb[t];  // /temperature (=0.25) + pos_bias
        }
        float m = sc[0];
#pragma unroll
        for (int t = 1; t < 5; ++t) m = fmaxf(m, sc[t]);
        float l = 0.f;
#pragma unroll
        for (int t = 0; t < 5; ++t) { sc[t] = __expf(sc[t] - m); l += sc[t]; }
        const float inv = 1.0f / l;
        f32x4 oo = {};
#pragma unroll
        for (int t = 0; t < 5; ++t)
#pragma unroll
          for (int rr = 0; rr < 4; ++rr) oo[rr] += sc[t] * vacc[u][j][t][rr];
#pragma unroll
        for (int rr = 0; rr < 4; ++rr) oo[rr] = oo[rr] * inv + bvr[rr];
        o[u][j] = oo;
      }
    }

    BAR_ONLY();  // bar_A: cross-wave ordering only (per-wave LDS reads are
                 // complete by data dependency); stage glls stay in flight

    // ---- write as_ overlay (first 16 KB of Xb; lane-linear b64) ----
#pragma unroll
    for (int u = 0; u < 2; ++u)
#pragma unroll
      for (int j = 0; j < 2; ++j) {
        union { f16 hh[4]; unsigned long long uu; } pk;
#pragma unroll
        for (int rr = 0; rr < 4; ++rr) pk.hh[rr] = (f16)o[u][j][rr];
        const int byte = (w << 10) + ((2 * j + (g4 >> 1)) << 8) + (c << 4)
                         + ((g4 & 1) << 3);
        *(unsigned long long*)(Xb + u * 8192 + byte) = pk.uu;
      }
    BAR_LGKM();  // bar_B: as_ ds_writes complete + visible to all waves

    // ---- projection (qkv accs dead here -> low pressure: unroll 4) ----
    f32x4 facc[2][2] = {};
#pragma unroll 4
    for (int k0 = 0; k0 < 8; ++k0) {
      const int wb = k0 * 512 + lane * 8;
      const f16x8 f0 = *(const f16x8*)(wfp + hA * 4096 + wb);
      const f16x8 f1 = *(const f16x8*)(wfp + (hA + 1) * 4096 + wb);
      const int abyte = (k0 << 10) + (g4 << 8) + (c << 4);
#pragma unroll
      for (int u = 0; u < 2; ++u) {
        const f16x8 af = *(const f16x8*)(Xb + u * 8192 + abyte);
        facc[u][0] = __builtin_amdgcn_mfma_f32_16x16x32_f16(af, f0, facc[u][0], 0, 0, 0);
        facc[u][1] = __builtin_amdgcn_mfma_f32_16x16x32_f16(af, f1, facc[u][1], 0, 0, 0);
      }
    }

    // ---- store (4 f32x4/wave; left pending across next pair-top) ----
#pragma unroll
    for (int u = 0; u < 2; ++u) {
      const int g = (pair0 + i) * 2 + u;
      const int b = g >> 10, s0 = (g & 1023) << 4;
#pragma unroll
      for (int j = 0; j < 2; ++j) {
        const int dg = (hA + j) * 16 + c;
        f32x4 vs = facc[u][j];
        const float bias = bp[dg];
#pragma unroll
        for (int rr = 0; rr < 4; ++rr) vs[rr] += bias;
        float* dst = out + ((size_t)b * 256 + dg) * SP + s0 + (g4 << 2);
        *(f32x4*)dst = vs;
      }
    }
    // no bar_C: next write to Xb is stage(i+2), behind next pair-top barrier
  }
}

extern "C" void kernel_launch(void* const* d_in, const int* in_sizes, int n_in,
                              void* d_out, int out_size, void* d_ws, size_t ws_size,
                              hipStream_t stream) {
  const float* x   = (const float*)d_in[0];
  const float* Wq  = (const float*)d_in[1];
  const float* bq  = (const float*)d_in[2];
  const float* Wkv = (const float*)d_in[3];
  const float* bkv = (const float*)d_in[4];
  const float* Wp  = (const float*)d_in[5];
  const float* bp  = (const float*)d_in[6];
  const float* pos = (const float*)d_in[7];

  f16* xf = (f16*)d_ws;                        // 168 MB
  f16* wf = (f16*)((char*)d_ws + XF_BYTES);    // 512 KB fragment weights

  prep_frag<<<64, 512, 0, stream>>>(Wq, Wkv, Wp, wf);
  xpose<<<10240, 256, 0, stream>>>(x, xf);
  fused<<<256, 512, 0, stream>>>(xf, bq, bkv, bp, pos, wf, (float*)d_out);
}